// Round 4
// baseline (435.697 us; speedup 1.0000x reference)
//
#include <hip/hip_runtime.h>

#define N 8192
#define D 128

typedef __attribute__((ext_vector_type(8))) short short8;   // 8 bf16 = 4 VGPRs
typedef __attribute__((ext_vector_type(4))) float float4v;  // MFMA C/D

__device__ __forceinline__ unsigned short f32_to_bf16(float f) {
    unsigned int u = __float_as_uint(f);
    unsigned int r = (u + 0x7fffu + ((u >> 16) & 1u)) >> 16;
    return (unsigned short)r;
}

__device__ __forceinline__ float wave_reduce(float p) {
    #pragma unroll
    for (int off = 32; off > 0; off >>= 1)
        p += __shfl_xor(p, off, 64);
    return p;
}

// ---------------- Prologue: ybf = bf16(W + b); reg partials = 0.05*||Y||^2 ----
__global__ __launch_bounds__(256)
void gf_prep_kernel(const float* __restrict__ W, const float* __restrict__ b,
                    unsigned short* __restrict__ ybf, float* __restrict__ regp) {
    __shared__ float s_ws[4];
    const int t = blockIdx.x * 256 + threadIdx.x;
    const int f = t * 4;                       // flat element index, 4 per thread
    const int dcol = f & (D - 1);
    const float4 wv = *(const float4*)(W + f);
    const float4 bv = *(const float4*)(b + dcol);
    const float y0 = wv.x + bv.x, y1 = wv.y + bv.y, y2 = wv.z + bv.z, y3 = wv.w + bv.w;

    ushort4 o;
    o.x = f32_to_bf16(y0); o.y = f32_to_bf16(y1);
    o.z = f32_to_bf16(y2); o.w = f32_to_bf16(y3);
    *(ushort4*)(ybf + f) = o;

    float s = y0*y0 + y1*y1 + y2*y2 + y3*y3;
    s = wave_reduce(s);
    const int lane = threadIdx.x & 63, w = threadIdx.x >> 6;
    if (lane == 0) s_ws[w] = s;
    __syncthreads();
    if (threadIdx.x == 0)
        regp[blockIdx.x] = 0.05f * (s_ws[0] + s_ws[1] + s_ws[2] + s_ws[3]);
}

// ---------------- Main: fused dense SDDMM + masked loss --------------------
// Grid 64x64; block tile 128(i) x 128(j); 4 waves, each owns 32 i-rows.
// Per wave: A-frags (2 i-subtiles x K=128) live in VGPRs across the j-loop.
// Per (jj, s): 4 chained mfma_f32_16x16x32_bf16 -> 16x16 C frag, then read
// the matching A fragment (coalesced 64B segments) and accumulate masked r^2.
__global__ __launch_bounds__(256, 4)
void gf_sddmm_kernel(const float* __restrict__ A,
                     const unsigned short* __restrict__ ybf,
                     float* __restrict__ partials) {
    __shared__ float s_ws[4];
    const int lane = threadIdx.x & 63;
    const int w    = threadIdx.x >> 6;
    const int i0   = blockIdx.x * 128 + w * 32;
    const int j0   = blockIdx.y * 128;
    const int r16  = lane & 15;
    const int quad = lane >> 4;

    // A-operand frags: lane holds Y[i0+s*16+r16][c*32+quad*8 .. +8]
    short8 afr[2][4];
    #pragma unroll
    for (int s = 0; s < 2; ++s) {
        const unsigned short* yrow = ybf + (size_t)(i0 + s * 16 + r16) * D;
        #pragma unroll
        for (int c = 0; c < 4; ++c)
            afr[s][c] = *(const short8*)(yrow + c * 32 + quad * 8);
    }

    float loss = 0.0f;
    for (int jj = 0; jj < 8; ++jj) {
        const int jbase = j0 + jj * 16;
        // B-operand frags: identical lane layout (B[k][n], n=lane&15)
        short8 bfr[4];
        {
            const unsigned short* yrow = ybf + (size_t)(jbase + r16) * D;
            #pragma unroll
            for (int c = 0; c < 4; ++c)
                bfr[c] = *(const short8*)(yrow + c * 32 + quad * 8);
        }
        #pragma unroll
        for (int s = 0; s < 2; ++s) {
            float4v acc = {0.f, 0.f, 0.f, 0.f};
            #pragma unroll
            for (int c = 0; c < 4; ++c)
                acc = __builtin_amdgcn_mfma_f32_16x16x32_bf16(afr[s][c], bfr[c], acc, 0, 0, 0);
            // C/D frag: col = lane&15, row = quad*4 + reg
            const int col = jbase + r16;
            #pragma unroll
            for (int r = 0; r < 4; ++r) {
                const int row = i0 + s * 16 + quad * 4 + r;
                const float a = A[(size_t)row * N + col];
                const float d = a - acc[r];
                loss += (a > 0.0f) ? d * d : 0.0f;
            }
        }
    }

    loss = wave_reduce(loss);
    if (lane == 0) s_ws[w] = loss;
    __syncthreads();
    if (threadIdx.x == 0)
        partials[blockIdx.y * gridDim.x + blockIdx.x] =
            0.5f * (s_ws[0] + s_ws[1] + s_ws[2] + s_ws[3]);
}

// ---------------- Final reduce: sum 4096 main + 1024 reg partials ----------
__global__ __launch_bounds__(256)
void gf_reduce_kernel(const float* __restrict__ parts, float* __restrict__ out) {
    __shared__ float s_ws[4];
    const int lane = threadIdx.x & 63, w = threadIdx.x >> 6;
    float s = 0.0f;
    for (int i = threadIdx.x; i < 4096 + 1024; i += 256) s += parts[i];
    s = wave_reduce(s);
    if (lane == 0) s_ws[w] = s;
    __syncthreads();
    if (threadIdx.x == 0) out[0] = s_ws[0] + s_ws[1] + s_ws[2] + s_ws[3];
}

extern "C" void kernel_launch(void* const* d_in, const int* in_sizes, int n_in,
                              void* d_out, int out_size, void* d_ws, size_t ws_size,
                              hipStream_t stream) {
    const float* A = (const float*)d_in[0];
    const float* W = (const float*)d_in[1];
    const float* b = (const float*)d_in[2];
    float* out = (float*)d_out;

    float* parts = (float*)d_ws;                        // [0,4096) main, [4096,5120) reg
    unsigned short* ybf = (unsigned short*)((float*)d_ws + 8192);  // 2 MB bf16 Y

    gf_prep_kernel<<<dim3(N * D / 1024), dim3(256), 0, stream>>>(W, b, ybf, parts + 4096);
    gf_sddmm_kernel<<<dim3(64, 64), dim3(256), 0, stream>>>(A, ybf, parts);
    gf_reduce_kernel<<<dim3(1), dim3(256), 0, stream>>>(parts, out);
}